// Round 3
// baseline (595.983 us; speedup 1.0000x reference)
//
#include <hip/hip_runtime.h>
#include <hip/hip_bf16.h>
#include <stdint.h>

// ---------- types / helpers ----------
typedef float f32x4 __attribute__((ext_vector_type(4)));
typedef __bf16 bf16x8 __attribute__((ext_vector_type(8)));

__device__ __forceinline__ float bf2f(unsigned short u) {
    unsigned int x = ((unsigned int)u) << 16;
    return __builtin_bit_cast(float, x);
}
__device__ __forceinline__ unsigned short f2bf(float f) {
    unsigned int x = __builtin_bit_cast(unsigned int, f);
    unsigned int lsb = (x >> 16) & 1u;
    x += 0x7fffu + lsb;            // round-to-nearest-even
    return (unsigned short)(x >> 16);
}

#define GLL16(gptr, lptr)                                                      \
    __builtin_amdgcn_global_load_lds(                                          \
        (const __attribute__((address_space(1))) void*)(gptr),                 \
        (__attribute__((address_space(3))) void*)(lptr), 16, 0, 0)

// ---------- fp32 -> bf16 convert (weights) ----------
__global__ __launch_bounds__(256) void cvt_kernel(
    const float* __restrict__ s, unsigned short* __restrict__ d, int n4)
{
    const int i = blockIdx.x * 256 + threadIdx.x;
    if (i >= n4) return;
    f32x4 v = ((const f32x4*)s)[i];
    ushort4 o;
    o.x = f2bf(v.x); o.y = f2bf(v.y); o.z = f2bf(v.z); o.w = f2bf(v.w);
    ((ushort4*)d)[i] = o;
}

// ---------- LayerNorm: fp32 in -> bf16 out, one wave per token (C=256) ----------
__global__ __launch_bounds__(256) void ln_kernel(
    const float* __restrict__ x, const float* __restrict__ g,
    const float* __restrict__ b, unsigned short* __restrict__ y)
{
    const int lane = threadIdx.x & 63, wave = threadIdx.x >> 6;
    const size_t tok = (size_t)blockIdx.x * 4 + wave;
    f32x4 v = *(const f32x4*)(x + tok * 256 + lane * 4);
    float s = v.x + v.y + v.z + v.w;
    float q = v.x * v.x + v.y * v.y + v.z * v.z + v.w * v.w;
#pragma unroll
    for (int o = 32; o; o >>= 1) {
        s += __shfl_xor(s, o, 64);
        q += __shfl_xor(q, o, 64);
    }
    float mean = s * (1.f / 256.f);
    float var  = q * (1.f / 256.f) - mean * mean;
    float rstd = rsqrtf(var + 1e-5f);
    f32x4 gr = *(const f32x4*)(g + lane * 4);
    f32x4 br = *(const f32x4*)(b + lane * 4);
    ushort4 o4;
    o4.x = f2bf((v.x - mean) * rstd * gr.x + br.x);
    o4.y = f2bf((v.y - mean) * rstd * gr.y + br.y);
    o4.z = f2bf((v.z - mean) * rstd * gr.z + br.z);
    o4.w = f2bf((v.w - mean) * rstd * gr.w + br.w);
    *(ushort4*)(y + tok * 256 + lane * 4) = o4;
}

// ---------- GEMM: C[M,N] = A[M,K](bf16) @ W[N,K](bf16)^T + bias(f32) ----------
// optional relu, optional fp32 residual, output bf16 or fp32.
// 128x128 tile, BK=32, 4 waves (2x2), each wave 4x4 mfma_f32_16x16x32_bf16.
// NOTE: res/C not __restrict__ — ffn2 passes res == C (in-place residual).
template <int RELU, int HASRES, int OUTF32>
__global__ __launch_bounds__(256) void gemm_bt(
    const unsigned short* __restrict__ A,    // [M,K] bf16
    const unsigned short* __restrict__ W,    // [N,K] bf16
    const float* __restrict__ bias,          // [N]   fp32
    const float* res,                        // [M,N] fp32 or null
    void* Cv,                                // [M,N] bf16 or fp32
    int M, int N, int K)
{
    __shared__ __align__(16) unsigned short As[128 * 32];
    __shared__ __align__(16) unsigned short Bs[128 * 32];

    const int t    = threadIdx.x;
    const int m0   = blockIdx.x * 128;
    const int n0   = blockIdx.y * 128;
    const int lane = t & 63;
    const int wave = t >> 6;
    const int wm = wave & 1, wn = wave >> 1;
    const int lr = lane & 15, kc = lane >> 4;

    f32x4 acc[4][4] = {};

    const int rowA = t >> 2;             // 0..63
    const int colA = (t & 3) * 8;        // 0,8,16,24
    const unsigned short* gA = A + (size_t)(m0 + rowA) * K + colA;
    const unsigned short* gB = W + (size_t)(n0 + rowA) * K + colA;

    for (int k0 = 0; k0 < K; k0 += 32) {
        GLL16(gA + k0, &As[t * 8]);
        GLL16(gA + (size_t)64 * K + k0, &As[2048 + t * 8]);
        GLL16(gB + k0, &Bs[t * 8]);
        GLL16(gB + (size_t)64 * K + k0, &Bs[2048 + t * 8]);
        __syncthreads();   // drains vmcnt(0) before s_barrier

        bf16x8 af[4], bf[4];
#pragma unroll
        for (int i = 0; i < 4; ++i) {
            af[i] = *(const bf16x8*)&As[(wm * 64 + i * 16 + lr) * 32 + kc * 8];
            bf[i] = *(const bf16x8*)&Bs[(wn * 64 + i * 16 + lr) * 32 + kc * 8];
        }
#pragma unroll
        for (int i = 0; i < 4; ++i)
#pragma unroll
            for (int j = 0; j < 4; ++j)
                acc[i][j] = __builtin_amdgcn_mfma_f32_16x16x32_bf16(
                    af[i], bf[j], acc[i][j], 0, 0, 0);
        __syncthreads();
    }

    // epilogue: C/D layout col=lane&15, row=(lane>>4)*4+reg
    float* Cf = (float*)Cv;
    unsigned short* Cb = (unsigned short*)Cv;
    const int row0 = m0 + wm * 64;
    const int col0 = n0 + wn * 64;
    const int cl = lane & 15;
    const int rq = (lane >> 4) * 4;
#pragma unroll
    for (int i = 0; i < 4; ++i) {
#pragma unroll
        for (int j = 0; j < 4; ++j) {
            const int col = col0 + j * 16 + cl;
            const float bv = bias[col];
#pragma unroll
            for (int r = 0; r < 4; ++r) {
                const int row = row0 + i * 16 + rq + r;
                float v = acc[i][j][r] + bv;
                if (RELU) v = fmaxf(v, 0.f);
                const size_t o = (size_t)row * N + col;
                if (HASRES) v += res[o];
                if (OUTF32) Cf[o] = v;
                else        Cb[o] = f2bf(v);
            }
        }
    }
}

// ---------- Per-token head-mix attention (bf16 in/out) ----------
// scores[h,g] = q[h,:].k[g,:]/sqrt(32); softmax over g;
// out[h,d] = sum_g attn[h,g] v[g,d].  One wave per token, lane = h*8+g.
__global__ __launch_bounds__(256) void attn_headmix(
    const unsigned short* __restrict__ qkv,  // [T,768] bf16 (q|k|v, 8 heads x 32)
    unsigned short* __restrict__ out,        // [T,256] bf16
    int T)
{
    const int lane = threadIdx.x & 63, wave = threadIdx.x >> 6;
    const int tok = blockIdx.x * 4 + wave;
    if (tok >= T) return;
    const unsigned short* base = qkv + (size_t)tok * 768;
    const int h = lane >> 3, g = lane & 7;

    float s = 0.f;
#pragma unroll
    for (int d8 = 0; d8 < 4; ++d8) {
        ushort4 qa = *(const ushort4*)(base + h * 32 + d8 * 8);
        ushort4 qb = *(const ushort4*)(base + h * 32 + d8 * 8 + 4);
        ushort4 ka = *(const ushort4*)(base + 256 + g * 32 + d8 * 8);
        ushort4 kb = *(const ushort4*)(base + 256 + g * 32 + d8 * 8 + 4);
        s += bf2f(qa.x) * bf2f(ka.x) + bf2f(qa.y) * bf2f(ka.y)
           + bf2f(qa.z) * bf2f(ka.z) + bf2f(qa.w) * bf2f(ka.w)
           + bf2f(qb.x) * bf2f(kb.x) + bf2f(qb.y) * bf2f(kb.y)
           + bf2f(qb.z) * bf2f(kb.z) + bf2f(qb.w) * bf2f(kb.w);
    }
    s *= 0.17677669529663687f;   // 1/sqrt(32)

    float mx = s;
#pragma unroll
    for (int o = 1; o < 8; o <<= 1) mx = fmaxf(mx, __shfl_xor(mx, o, 64));
    float e = __expf(s - mx);
    float sum = e;
#pragma unroll
    for (int o = 1; o < 8; o <<= 1) sum += __shfl_xor(sum, o, 64);
    const float a = e / sum;

    float o0 = 0.f, o1 = 0.f, o2 = 0.f, o3 = 0.f;
#pragma unroll
    for (int gg = 0; gg < 8; ++gg) {
        const float ag = __shfl(a, (lane & 56) | gg, 64);
        ushort4 vv = *(const ushort4*)(base + 512 + gg * 32 + g * 4);
        o0 += ag * bf2f(vv.x);
        o1 += ag * bf2f(vv.y);
        o2 += ag * bf2f(vv.z);
        o3 += ag * bf2f(vv.w);
    }
    ushort4 ov;
    ov.x = f2bf(o0); ov.y = f2bf(o1); ov.z = f2bf(o2); ov.w = f2bf(o3);
    *(ushort4*)(out + (size_t)tok * 256 + lane * 4) = ov;   // c = h*32+g*4 = lane*4
}

// ---------- launch ----------
// fp32 I/O, bf16 internal. Residual trunk stays fp32 on d_out.
// ws layout (ushort elems), total 42 MB:
//   [0, 786432)      wb: converted weights (qkv_w | proj_w | ffn_w1 | ffn_w2)
//   [1M, 5M)         xnc  [TCH,256] bf16  (LN1 out, per chunk) / x2nc in phase B
//   [5M, 9M)         attc [TCH,256] bf16  (attn out, per chunk)
//   [9M, 21M)        qkvb [TCH,768] bf16  (per chunk)
//   [5M, 21M)        h    [TCH,1024] bf16 (phase B, reuses attc+qkvb)
extern "C" void kernel_launch(void* const* d_in, const int* in_sizes, int n_in,
                              void* d_out, int out_size, void* d_ws, size_t ws_size,
                              hipStream_t stream)
{
    const float* x      = (const float*)d_in[0];
    const float* ln1_g  = (const float*)d_in[1];
    const float* ln1_b  = (const float*)d_in[2];
    const float* qkv_w  = (const float*)d_in[3];
    const float* qkv_b  = (const float*)d_in[4];
    const float* proj_w = (const float*)d_in[5];
    const float* proj_b = (const float*)d_in[6];
    const float* ln2_g  = (const float*)d_in[7];
    const float* ln2_b  = (const float*)d_in[8];
    const float* ffn_w1 = (const float*)d_in[9];
    const float* ffn_b1 = (const float*)d_in[10];
    const float* ffn_w2 = (const float*)d_in[11];
    const float* ffn_b2 = (const float*)d_in[12];
    float* xo = (float*)d_out;            // fp32 trunk + final out

    const int TCH = 16384, NCH = 4;       // 65536 tokens total
    const size_t MEG = 1024 * 1024;
    unsigned short* ws = (unsigned short*)d_ws;
    unsigned short* qkv_wb = ws;                    // 196608
    unsigned short* proj_wb = ws + 196608;          // 65536
    unsigned short* ffn_w1b = ws + 262144;          // 262144
    unsigned short* ffn_w2b = ws + 524288;          // 262144
    unsigned short* xnc  = ws + 1 * MEG;            // [TCH,256]
    unsigned short* attc = ws + 5 * MEG;            // [TCH,256]
    unsigned short* qkvb = ws + 9 * MEG;            // [TCH,768]
    unsigned short* x2nc = ws + 1 * MEG;            // [TCH,256] (phase B)
    unsigned short* h    = ws + 5 * MEG;            // [TCH,1024] (phase B)

    // 0) convert weights to bf16
    cvt_kernel<<<192, 256, 0, stream>>>(qkv_w, qkv_wb, 196608 / 4);
    cvt_kernel<<<64, 256, 0, stream>>>(proj_w, proj_wb, 65536 / 4);
    cvt_kernel<<<256, 256, 0, stream>>>(ffn_w1, ffn_w1b, 262144 / 4);
    cvt_kernel<<<256, 256, 0, stream>>>(ffn_w2, ffn_w2b, 262144 / 4);

    // Phase A per chunk: LN1 -> qkv -> attn -> proj(+x residual) -> xo (fp32)
    for (int c = 0; c < NCH; ++c) {
        const size_t off = (size_t)c * TCH;
        ln_kernel<<<TCH / 4, 256, 0, stream>>>(x + off * 256, ln1_g, ln1_b, xnc);
        gemm_bt<0, 0, 0><<<dim3(TCH / 128, 6), 256, 0, stream>>>(
            xnc, qkv_wb, qkv_b, nullptr, qkvb, TCH, 768, 256);
        attn_headmix<<<TCH / 4, 256, 0, stream>>>(qkvb, attc, TCH);
        gemm_bt<0, 1, 1><<<dim3(TCH / 128, 2), 256, 0, stream>>>(
            attc, proj_wb, proj_b, x + off * 256, xo + off * 256, TCH, 256, 256);
    }

    // Phase B per chunk: LN2 -> ffn1(relu) -> ffn2(+xo residual, in-place fp32)
    for (int c = 0; c < NCH; ++c) {
        const size_t off = (size_t)c * TCH;
        ln_kernel<<<TCH / 4, 256, 0, stream>>>(xo + off * 256, ln2_g, ln2_b, x2nc);
        gemm_bt<1, 0, 0><<<dim3(TCH / 128, 8), 256, 0, stream>>>(
            x2nc, ffn_w1b, ffn_b1, nullptr, h, TCH, 1024, 256);
        gemm_bt<0, 1, 1><<<dim3(TCH / 128, 2), 256, 0, stream>>>(
            h, ffn_w2b, ffn_b2, xo + off * 256, xo + off * 256, TCH, 256, 1024);
    }
}

// Round 4
// 524.125 us; speedup vs baseline: 1.1371x; 1.1371x over previous
//
#include <hip/hip_runtime.h>
#include <hip/hip_bf16.h>
#include <stdint.h>

// ---------- types / helpers ----------
typedef float f32x4 __attribute__((ext_vector_type(4)));
typedef __bf16 bf16x8 __attribute__((ext_vector_type(8)));

__device__ __forceinline__ float bf2f(unsigned short u) {
    unsigned int x = ((unsigned int)u) << 16;
    return __builtin_bit_cast(float, x);
}
__device__ __forceinline__ unsigned short f2bf(float f) {
    unsigned int x = __builtin_bit_cast(unsigned int, f);
    unsigned int lsb = (x >> 16) & 1u;
    x += 0x7fffu + lsb;            // round-to-nearest-even
    return (unsigned short)(x >> 16);
}

#define GLL16(gptr, lptr)                                                      \
    __builtin_amdgcn_global_load_lds(                                          \
        (const __attribute__((address_space(1))) void*)(gptr),                 \
        (__attribute__((address_space(3))) void*)(lptr), 16, 0, 0)

// ---------- fp32 -> bf16 convert, all 4 weight matrices in one launch ----------
// dst layout (ushort4 units): qkv_w[0,49152) proj_w[49152,65536)
// ffn_w1[65536,131072) ffn_w2[131072,196608)
__global__ __launch_bounds__(256) void cvt4_kernel(
    const float* __restrict__ w0, const float* __restrict__ w1,
    const float* __restrict__ w2, const float* __restrict__ w3,
    unsigned short* __restrict__ dst)
{
    const int i = blockIdx.x * 256 + threadIdx.x;   // 0..196607
    const float* s; int off;
    if      (i <  49152) { s = w0; off = 0; }
    else if (i <  65536) { s = w1; off = 49152; }
    else if (i < 131072) { s = w2; off = 65536; }
    else                 { s = w3; off = 131072; }
    f32x4 v = ((const f32x4*)s)[i - off];
    ushort4 o;
    o.x = f2bf(v.x); o.y = f2bf(v.y); o.z = f2bf(v.z); o.w = f2bf(v.w);
    ((ushort4*)dst)[i] = o;
}

// ---------- LayerNorm: fp32 in -> bf16 out, one wave per token (C=256) ----------
__global__ __launch_bounds__(256) void ln_kernel(
    const float* __restrict__ x, const float* __restrict__ g,
    const float* __restrict__ b, unsigned short* __restrict__ y)
{
    const int lane = threadIdx.x & 63, wave = threadIdx.x >> 6;
    const size_t tok = (size_t)blockIdx.x * 4 + wave;
    f32x4 v = *(const f32x4*)(x + tok * 256 + lane * 4);
    float s = v.x + v.y + v.z + v.w;
    float q = v.x * v.x + v.y * v.y + v.z * v.z + v.w * v.w;
#pragma unroll
    for (int o = 32; o; o >>= 1) {
        s += __shfl_xor(s, o, 64);
        q += __shfl_xor(q, o, 64);
    }
    float mean = s * (1.f / 256.f);
    float var  = q * (1.f / 256.f) - mean * mean;
    float rstd = rsqrtf(var + 1e-5f);
    f32x4 gr = *(const f32x4*)(g + lane * 4);
    f32x4 br = *(const f32x4*)(b + lane * 4);
    ushort4 o4;
    o4.x = f2bf((v.x - mean) * rstd * gr.x + br.x);
    o4.y = f2bf((v.y - mean) * rstd * gr.y + br.y);
    o4.z = f2bf((v.z - mean) * rstd * gr.z + br.z);
    o4.w = f2bf((v.w - mean) * rstd * gr.w + br.w);
    *(ushort4*)(y + tok * 256 + lane * 4) = o4;
}

// ---------- GEMM: C[M,N] = A[M,K](bf16) @ W[N,K](bf16)^T + bias(f32) ----------
// 128x128 tile, BK=64, 4 waves (2x2), each wave 4x4 mfma_f32_16x16x32_bf16 x2.
// LDS layout XOR-swizzled: row r's 8-short chunk c stored at slot c ^ (r&7).
// The swizzle is applied on the GLOBAL address (gcol) so that the
// global_load_lds destination stays base + lane*16B (HW constraint).
// Reads then hit each bank exactly 2x per 16-lane group (conflict-free).
// NOTE: res/C not __restrict__ — ffn2 passes res == C (in-place residual).
template <int RELU, int HASRES, int OUTF32>
__global__ __launch_bounds__(256) void gemm_bt(
    const unsigned short* __restrict__ A,    // [M,K] bf16
    const unsigned short* __restrict__ W,    // [N,K] bf16
    const float* __restrict__ bias,          // [N]   fp32
    const float* res,                        // [M,N] fp32 or null
    void* Cv,                                // [M,N] bf16 or fp32
    int M, int N, int K)
{
    __shared__ __align__(16) unsigned short As[128 * 64];
    __shared__ __align__(16) unsigned short Bs[128 * 64];

    const int t    = threadIdx.x;
    const int m0   = blockIdx.x * 128;
    const int n0   = blockIdx.y * 128;
    const int lane = t & 63;
    const int wave = t >> 6;
    const int wm = wave & 1, wn = wave >> 1;
    const int lr = lane & 15, kc = lane >> 4;

    f32x4 acc[4][4] = {};

    // staging map: call w covers rows w*32..w*32+31; thread t -> row w*32+(t>>3),
    // stored chunk sc = t&7 at LDS slot (w*256+t)*8 shorts; global chunk = sc^(row&7).
    const int rA   = t >> 3;                       // 0..31
    const int gcol = ((t & 7) ^ (rA & 7)) * 8;     // row&7 == rA&7 (w*32 ≡ 0 mod 8)
    const unsigned short* gA = A + (size_t)(m0 + rA) * K + gcol;
    const unsigned short* gB = W + (size_t)(n0 + rA) * K + gcol;

    for (int k0 = 0; k0 < K; k0 += 64) {
#pragma unroll
        for (int w = 0; w < 4; ++w) {
            GLL16(gA + (size_t)(w * 32) * K + k0, &As[(w * 256 + t) * 8]);
            GLL16(gB + (size_t)(w * 32) * K + k0, &Bs[(w * 256 + t) * 8]);
        }
        __syncthreads();   // drains vmcnt(0) before s_barrier

#pragma unroll
        for (int hh = 0; hh < 2; ++hh) {
            bf16x8 af[4], bf[4];
#pragma unroll
            for (int i = 0; i < 4; ++i) {
                const int ra = wm * 64 + i * 16 + lr;
                const int rb = wn * 64 + i * 16 + lr;
                af[i] = *(const bf16x8*)&As[ra * 64 + ((hh * 4 + kc) ^ (ra & 7)) * 8];
                bf[i] = *(const bf16x8*)&Bs[rb * 64 + ((hh * 4 + kc) ^ (rb & 7)) * 8];
            }
#pragma unroll
            for (int i = 0; i < 4; ++i)
#pragma unroll
                for (int j = 0; j < 4; ++j)
                    acc[i][j] = __builtin_amdgcn_mfma_f32_16x16x32_bf16(
                        af[i], bf[j], acc[i][j], 0, 0, 0);
        }
        __syncthreads();
    }

    // epilogue: C/D layout col=lane&15, row=(lane>>4)*4+reg
    float* Cf = (float*)Cv;
    unsigned short* Cb = (unsigned short*)Cv;
    const int row0 = m0 + wm * 64;
    const int col0 = n0 + wn * 64;
    const int cl = lane & 15;
    const int rq = (lane >> 4) * 4;
#pragma unroll
    for (int i = 0; i < 4; ++i) {
#pragma unroll
        for (int j = 0; j < 4; ++j) {
            const int col = col0 + j * 16 + cl;
            const float bv = bias[col];
#pragma unroll
            for (int r = 0; r < 4; ++r) {
                const int row = row0 + i * 16 + rq + r;
                float v = acc[i][j][r] + bv;
                if (RELU) v = fmaxf(v, 0.f);
                const size_t o = (size_t)row * N + col;
                if (HASRES) v += res[o];
                if (OUTF32) Cf[o] = v;
                else        Cb[o] = f2bf(v);
            }
        }
    }
}

// ---------- Per-token head-mix attention (bf16 in/out) ----------
// scores[h,g] = q[h,:].k[g,:]/sqrt(32); softmax over g;
// out[h,d] = sum_g attn[h,g] v[g,d].  One wave per token, lane = h*8+g.
__global__ __launch_bounds__(256) void attn_headmix(
    const unsigned short* __restrict__ qkv,  // [T,768] bf16 (q|k|v, 8 heads x 32)
    unsigned short* __restrict__ out,        // [T,256] bf16
    int T)
{
    const int lane = threadIdx.x & 63, wave = threadIdx.x >> 6;
    const int tok = blockIdx.x * 4 + wave;
    if (tok >= T) return;
    const unsigned short* base = qkv + (size_t)tok * 768;
    const int h = lane >> 3, g = lane & 7;

    float s = 0.f;
#pragma unroll
    for (int d8 = 0; d8 < 4; ++d8) {
        ushort4 qa = *(const ushort4*)(base + h * 32 + d8 * 8);
        ushort4 qb = *(const ushort4*)(base + h * 32 + d8 * 8 + 4);
        ushort4 ka = *(const ushort4*)(base + 256 + g * 32 + d8 * 8);
        ushort4 kb = *(const ushort4*)(base + 256 + g * 32 + d8 * 8 + 4);
        s += bf2f(qa.x) * bf2f(ka.x) + bf2f(qa.y) * bf2f(ka.y)
           + bf2f(qa.z) * bf2f(ka.z) + bf2f(qa.w) * bf2f(ka.w)
           + bf2f(qb.x) * bf2f(kb.x) + bf2f(qb.y) * bf2f(kb.y)
           + bf2f(qb.z) * bf2f(kb.z) + bf2f(qb.w) * bf2f(kb.w);
    }
    s *= 0.17677669529663687f;   // 1/sqrt(32)

    float mx = s;
#pragma unroll
    for (int o = 1; o < 8; o <<= 1) mx = fmaxf(mx, __shfl_xor(mx, o, 64));
    float e = __expf(s - mx);
    float sum = e;
#pragma unroll
    for (int o = 1; o < 8; o <<= 1) sum += __shfl_xor(sum, o, 64);
    const float a = e / sum;

    float o0 = 0.f, o1 = 0.f, o2 = 0.f, o3 = 0.f;
#pragma unroll
    for (int gg = 0; gg < 8; ++gg) {
        const float ag = __shfl(a, (lane & 56) | gg, 64);
        ushort4 vv = *(const ushort4*)(base + 512 + gg * 32 + g * 4);
        o0 += ag * bf2f(vv.x);
        o1 += ag * bf2f(vv.y);
        o2 += ag * bf2f(vv.z);
        o3 += ag * bf2f(vv.w);
    }
    ushort4 ov;
    ov.x = f2bf(o0); ov.y = f2bf(o1); ov.z = f2bf(o2); ov.w = f2bf(o3);
    *(ushort4*)(out + (size_t)tok * 256 + lane * 4) = ov;   // c = h*32+g*4 = lane*4
}

// ---------- launch ----------
// fp32 I/O, bf16 internal, fp32 residual trunk on d_out. UN-CHUNKED.
// ws layout (ushort elems; ws_size = 256 MiB = 128M ushorts, peak use 162 MB):
//   [0, 786432)     wb: converted weights (qkv|proj|ffn1|ffn2)
//   [1M, 17M)       xn  [M,256] bf16 (LN1 out)     / x2n in phase B
//   [17M, 33M)      att [M,256] bf16 (attn out)
//   [33M, 81M)      qkv [M,768] bf16
//   [17M, 81M)      h   [M,1024] bf16 (phase B; att+qkv dead)
extern "C" void kernel_launch(void* const* d_in, const int* in_sizes, int n_in,
                              void* d_out, int out_size, void* d_ws, size_t ws_size,
                              hipStream_t stream)
{
    const float* x      = (const float*)d_in[0];
    const float* ln1_g  = (const float*)d_in[1];
    const float* ln1_b  = (const float*)d_in[2];
    const float* qkv_w  = (const float*)d_in[3];
    const float* qkv_b  = (const float*)d_in[4];
    const float* proj_w = (const float*)d_in[5];
    const float* proj_b = (const float*)d_in[6];
    const float* ln2_g  = (const float*)d_in[7];
    const float* ln2_b  = (const float*)d_in[8];
    const float* ffn_w1 = (const float*)d_in[9];
    const float* ffn_b1 = (const float*)d_in[10];
    const float* ffn_w2 = (const float*)d_in[11];
    const float* ffn_b2 = (const float*)d_in[12];
    float* xo = (float*)d_out;            // fp32 trunk + final out

    const int M = 65536;
    const size_t MEG = 1024 * 1024;
    unsigned short* ws = (unsigned short*)d_ws;
    unsigned short* qkv_wb  = ws;                   // 196608
    unsigned short* proj_wb = ws + 196608;          // 65536
    unsigned short* ffn_w1b = ws + 262144;          // 262144
    unsigned short* ffn_w2b = ws + 524288;          // 262144
    unsigned short* xn   = ws + 1 * MEG;            // [M,256]
    unsigned short* att  = ws + 17 * MEG;           // [M,256]
    unsigned short* qkvb = ws + 33 * MEG;           // [M,768]
    unsigned short* x2n  = ws + 1 * MEG;            // [M,256] (phase B)
    unsigned short* h    = ws + 17 * MEG;           // [M,1024] (phase B)

    cvt4_kernel<<<768, 256, 0, stream>>>(qkv_w, proj_w, ffn_w1, ffn_w2, ws);

    ln_kernel<<<M / 4, 256, 0, stream>>>(x, ln1_g, ln1_b, xn);
    gemm_bt<0, 0, 0><<<dim3(M / 128, 6), 256, 0, stream>>>(
        xn, qkv_wb, qkv_b, nullptr, qkvb, M, 768, 256);
    attn_headmix<<<M / 4, 256, 0, stream>>>(qkvb, att, M);
    gemm_bt<0, 1, 1><<<dim3(M / 128, 2), 256, 0, stream>>>(
        att, proj_wb, proj_b, x, xo, M, 256, 256);
    ln_kernel<<<M / 4, 256, 0, stream>>>(xo, ln2_g, ln2_b, x2n);
    gemm_bt<1, 0, 0><<<dim3(M / 128, 8), 256, 0, stream>>>(
        x2n, ffn_w1b, ffn_b1, nullptr, h, M, 1024, 256);
    gemm_bt<0, 1, 1><<<dim3(M / 128, 2), 256, 0, stream>>>(
        h, ffn_w2b, ffn_b2, xo, xo, M, 256, 1024);
}

// Round 5
// 463.886 us; speedup vs baseline: 1.2848x; 1.1299x over previous
//
#include <hip/hip_runtime.h>
#include <hip/hip_bf16.h>
#include <stdint.h>

// ---------- types / helpers ----------
typedef float f32x4 __attribute__((ext_vector_type(4)));
typedef __bf16 bf16x8 __attribute__((ext_vector_type(8)));
typedef unsigned short ushort8 __attribute__((ext_vector_type(8)));

__device__ __forceinline__ float bf2f(unsigned short u) {
    unsigned int x = ((unsigned int)u) << 16;
    return __builtin_bit_cast(float, x);
}
__device__ __forceinline__ unsigned short f2bf(float f) {
    unsigned int x = __builtin_bit_cast(unsigned int, f);
    unsigned int lsb = (x >> 16) & 1u;
    x += 0x7fffu + lsb;            // round-to-nearest-even
    return (unsigned short)(x >> 16);
}

#define GLL16(gptr, lptr)                                                      \
    __builtin_amdgcn_global_load_lds(                                          \
        (const __attribute__((address_space(1))) void*)(gptr),                 \
        (__attribute__((address_space(3))) void*)(lptr), 16, 0, 0)

// ---------- fp32 -> bf16 convert, all 4 weight matrices in one launch ----------
__global__ __launch_bounds__(256) void cvt4_kernel(
    const float* __restrict__ w0, const float* __restrict__ w1,
    const float* __restrict__ w2, const float* __restrict__ w3,
    unsigned short* __restrict__ dst)
{
    const int i = blockIdx.x * 256 + threadIdx.x;   // 0..196607
    const float* s; int off;
    if      (i <  49152) { s = w0; off = 0; }
    else if (i <  65536) { s = w1; off = 49152; }
    else if (i < 131072) { s = w2; off = 65536; }
    else                 { s = w3; off = 131072; }
    f32x4 v = ((const f32x4*)s)[i - off];
    ushort4 o;
    o.x = f2bf(v.x); o.y = f2bf(v.y); o.z = f2bf(v.z); o.w = f2bf(v.w);
    ((ushort4*)dst)[i] = o;
}

// ---------- LayerNorm (LN1): fp32 in -> bf16 out, one wave per token ----------
__global__ __launch_bounds__(256) void ln_kernel(
    const float* __restrict__ x, const float* __restrict__ g,
    const float* __restrict__ b, unsigned short* __restrict__ y)
{
    const int lane = threadIdx.x & 63, wave = threadIdx.x >> 6;
    const size_t tok = (size_t)blockIdx.x * 4 + wave;
    f32x4 v = *(const f32x4*)(x + tok * 256 + lane * 4);
    float s = v.x + v.y + v.z + v.w;
    float q = v.x * v.x + v.y * v.y + v.z * v.z + v.w * v.w;
#pragma unroll
    for (int o = 32; o; o >>= 1) {
        s += __shfl_xor(s, o, 64);
        q += __shfl_xor(q, o, 64);
    }
    float mean = s * (1.f / 256.f);
    float var  = q * (1.f / 256.f) - mean * mean;
    float rstd = rsqrtf(var + 1e-5f);
    f32x4 gr = *(const f32x4*)(g + lane * 4);
    f32x4 br = *(const f32x4*)(b + lane * 4);
    ushort4 o4;
    o4.x = f2bf((v.x - mean) * rstd * gr.x + br.x);
    o4.y = f2bf((v.y - mean) * rstd * gr.y + br.y);
    o4.z = f2bf((v.z - mean) * rstd * gr.z + br.z);
    o4.w = f2bf((v.w - mean) * rstd * gr.w + br.w);
    *(ushort4*)(y + tok * 256 + lane * 4) = o4;
}

// ---------- GEMM (phase A: qkv / proj), unchanged from R4 ----------
template <int RELU, int HASRES, int OUTF32>
__global__ __launch_bounds__(256) void gemm_bt(
    const unsigned short* __restrict__ A,    // [M,K] bf16
    const unsigned short* __restrict__ W,    // [N,K] bf16
    const float* __restrict__ bias,          // [N]   fp32
    const float* res,                        // [M,N] fp32 or null
    void* Cv,                                // [M,N] bf16 or fp32
    int M, int N, int K)
{
    __shared__ __align__(16) unsigned short As[128 * 64];
    __shared__ __align__(16) unsigned short Bs[128 * 64];

    const int t    = threadIdx.x;
    const int m0   = blockIdx.x * 128;
    const int n0   = blockIdx.y * 128;
    const int lane = t & 63;
    const int wave = t >> 6;
    const int wm = wave & 1, wn = wave >> 1;
    const int lr = lane & 15, kc = lane >> 4;

    f32x4 acc[4][4] = {};

    const int rA   = t >> 3;                       // 0..31
    const int gcol = ((t & 7) ^ (rA & 7)) * 8;
    const unsigned short* gA = A + (size_t)(m0 + rA) * K + gcol;
    const unsigned short* gB = W + (size_t)(n0 + rA) * K + gcol;

    for (int k0 = 0; k0 < K; k0 += 64) {
#pragma unroll
        for (int w = 0; w < 4; ++w) {
            GLL16(gA + (size_t)(w * 32) * K + k0, &As[(w * 256 + t) * 8]);
            GLL16(gB + (size_t)(w * 32) * K + k0, &Bs[(w * 256 + t) * 8]);
        }
        __syncthreads();

#pragma unroll
        for (int hh = 0; hh < 2; ++hh) {
            bf16x8 af[4], bf[4];
#pragma unroll
            for (int i = 0; i < 4; ++i) {
                const int ra = wm * 64 + i * 16 + lr;
                const int rb = wn * 64 + i * 16 + lr;
                af[i] = *(const bf16x8*)&As[ra * 64 + ((hh * 4 + kc) ^ (ra & 7)) * 8];
                bf[i] = *(const bf16x8*)&Bs[rb * 64 + ((hh * 4 + kc) ^ (rb & 7)) * 8];
            }
#pragma unroll
            for (int i = 0; i < 4; ++i)
#pragma unroll
                for (int j = 0; j < 4; ++j)
                    acc[i][j] = __builtin_amdgcn_mfma_f32_16x16x32_bf16(
                        af[i], bf[j], acc[i][j], 0, 0, 0);
        }
        __syncthreads();
    }

    float* Cf = (float*)Cv;
    unsigned short* Cb = (unsigned short*)Cv;
    const int row0 = m0 + wm * 64;
    const int col0 = n0 + wn * 64;
    const int cl = lane & 15;
    const int rq = (lane >> 4) * 4;
#pragma unroll
    for (int i = 0; i < 4; ++i) {
#pragma unroll
        for (int j = 0; j < 4; ++j) {
            const int col = col0 + j * 16 + cl;
            const float bv = bias[col];
#pragma unroll
            for (int r = 0; r < 4; ++r) {
                const int row = row0 + i * 16 + rq + r;
                float v = acc[i][j][r] + bv;
                if (RELU) v = fmaxf(v, 0.f);
                const size_t o = (size_t)row * N + col;
                if (HASRES) v += res[o];
                if (OUTF32) Cf[o] = v;
                else        Cb[o] = f2bf(v);
            }
        }
    }
}

// ---------- Per-token head-mix attention (bf16 in/out), unchanged ----------
__global__ __launch_bounds__(256) void attn_headmix(
    const unsigned short* __restrict__ qkv,  // [T,768] bf16
    unsigned short* __restrict__ out,        // [T,256] bf16
    int T)
{
    const int lane = threadIdx.x & 63, wave = threadIdx.x >> 6;
    const int tok = blockIdx.x * 4 + wave;
    if (tok >= T) return;
    const unsigned short* base = qkv + (size_t)tok * 768;
    const int h = lane >> 3, g = lane & 7;

    float s = 0.f;
#pragma unroll
    for (int d8 = 0; d8 < 4; ++d8) {
        ushort4 qa = *(const ushort4*)(base + h * 32 + d8 * 8);
        ushort4 qb = *(const ushort4*)(base + h * 32 + d8 * 8 + 4);
        ushort4 ka = *(const ushort4*)(base + 256 + g * 32 + d8 * 8);
        ushort4 kb = *(const ushort4*)(base + 256 + g * 32 + d8 * 8 + 4);
        s += bf2f(qa.x) * bf2f(ka.x) + bf2f(qa.y) * bf2f(ka.y)
           + bf2f(qa.z) * bf2f(ka.z) + bf2f(qa.w) * bf2f(ka.w)
           + bf2f(qb.x) * bf2f(kb.x) + bf2f(qb.y) * bf2f(kb.y)
           + bf2f(qb.z) * bf2f(kb.z) + bf2f(qb.w) * bf2f(kb.w);
    }
    s *= 0.17677669529663687f;

    float mx = s;
#pragma unroll
    for (int o = 1; o < 8; o <<= 1) mx = fmaxf(mx, __shfl_xor(mx, o, 64));
    float e = __expf(s - mx);
    float sum = e;
#pragma unroll
    for (int o = 1; o < 8; o <<= 1) sum += __shfl_xor(sum, o, 64);
    const float a = e / sum;

    float o0 = 0.f, o1 = 0.f, o2 = 0.f, o3 = 0.f;
#pragma unroll
    for (int gg = 0; gg < 8; ++gg) {
        const float ag = __shfl(a, (lane & 56) | gg, 64);
        ushort4 vv = *(const ushort4*)(base + 512 + gg * 32 + g * 4);
        o0 += ag * bf2f(vv.x);
        o1 += ag * bf2f(vv.y);
        o2 += ag * bf2f(vv.z);
        o3 += ag * bf2f(vv.w);
    }
    ushort4 ov;
    ov.x = f2bf(o0); ov.y = f2bf(o1); ov.z = f2bf(o2); ov.w = f2bf(o3);
    *(ushort4*)(out + (size_t)tok * 256 + lane * 4) = ov;
}

// ---------- Fused LN2 + FFN1(relu) + FFN2 + residual, in-place on xo ----------
// Block = 128 rows, 512 threads (8 waves). LDS 144 KB -> 1 block/CU.
// A (LN2 output, bf16) staged once; 16 hidden-chunks of 64:
//   stage W1c[64,256] + W2c[256,64] -> h = relu(A@W1c^T + b1) (bf16, LDS)
//   -> out[128,256] += h @ W2c^T  (fp32 accum in VGPRs)
// epilogue: out + b2 + xo -> xo (fp32).
// All LDS tiles use the low-3-bit XOR chunk swizzle (conflict-free b128 reads).
__global__ __launch_bounds__(512, 2) void ffn_fused(
    float* xo,                               // [M,256] fp32, read + written
    const float* __restrict__ ln2_g, const float* __restrict__ ln2_b,
    const unsigned short* __restrict__ w1,   // [1024,256] bf16
    const float* __restrict__ b1p,           // [1024]
    const unsigned short* __restrict__ w2,   // [256,1024] bf16
    const float* __restrict__ b2p)           // [256]
{
    __shared__ __align__(16) unsigned short As[128 * 256];  // 64 KB
    __shared__ __align__(16) unsigned short W1s[64 * 256];  // 32 KB
    __shared__ __align__(16) unsigned short W2s[256 * 64];  // 32 KB
    __shared__ __align__(16) unsigned short Hs[128 * 64];   // 16 KB

    const int t = threadIdx.x;               // 0..511
    const int lane = t & 63, wave = t >> 6;
    const int m0 = blockIdx.x * 128;
    const int lr = lane & 15, kc = lane >> 4;
    const int cl = lane & 15, rq = (lane >> 4) * 4;
    const int wm = wave & 1, wn = wave >> 1; // wn in 0..3

    // ---- phase 0: LN2 of the 128-row tile, write bf16 to As (swizzled) ----
    {
        const int row0 = t >> 2;             // 0..127
        const int seg  = t & 3;              // 64-float segment
        const float* xrp = xo + (size_t)(m0 + row0) * 256 + seg * 64;
        f32x4 xv[16];
#pragma unroll
        for (int i = 0; i < 16; ++i) xv[i] = ((const f32x4*)xrp)[i];
        float s = 0.f, q = 0.f;
#pragma unroll
        for (int i = 0; i < 16; ++i) {
            s += xv[i].x + xv[i].y + xv[i].z + xv[i].w;
            q += xv[i].x * xv[i].x + xv[i].y * xv[i].y
               + xv[i].z * xv[i].z + xv[i].w * xv[i].w;
        }
        s += __shfl_xor(s, 1, 64); q += __shfl_xor(q, 1, 64);
        s += __shfl_xor(s, 2, 64); q += __shfl_xor(q, 2, 64);
        const float mean = s * (1.f / 256.f);
        const float rstd = rsqrtf(q * (1.f / 256.f) - mean * mean + 1e-5f);
#pragma unroll
        for (int c8 = 0; c8 < 8; ++c8) {
            const f32x4 g0 = ((const f32x4*)(ln2_g + seg * 64 + c8 * 8))[0];
            const f32x4 g1 = ((const f32x4*)(ln2_g + seg * 64 + c8 * 8))[1];
            const f32x4 bb0 = ((const f32x4*)(ln2_b + seg * 64 + c8 * 8))[0];
            const f32x4 bb1 = ((const f32x4*)(ln2_b + seg * 64 + c8 * 8))[1];
            const f32x4 a0 = xv[c8 * 2], a1 = xv[c8 * 2 + 1];
            ushort8 o;
            o[0] = f2bf((a0.x - mean) * rstd * g0.x + bb0.x);
            o[1] = f2bf((a0.y - mean) * rstd * g0.y + bb0.y);
            o[2] = f2bf((a0.z - mean) * rstd * g0.z + bb0.z);
            o[3] = f2bf((a0.w - mean) * rstd * g0.w + bb0.w);
            o[4] = f2bf((a1.x - mean) * rstd * g1.x + bb1.x);
            o[5] = f2bf((a1.y - mean) * rstd * g1.y + bb1.y);
            o[6] = f2bf((a1.z - mean) * rstd * g1.z + bb1.z);
            o[7] = f2bf((a1.w - mean) * rstd * g1.w + bb1.w);
            const int gc = seg * 8 + c8;     // global chunk 0..31
            const int sc = (gc & ~7) | ((gc & 7) ^ (row0 & 7));
            *(ushort8*)&As[row0 * 256 + sc * 8] = o;
        }
    }

    f32x4 acc[4][4] = {};                    // out tile: rows wm*64, cols wn*64

    for (int hc = 0; hc < 16; ++hc) {
        // ---- stage W1 chunk [64 x 256] and W2 chunk [256 x 64] ----
#pragma unroll
        for (int j = 0; j < 4; ++j) {
            const int s1 = j * 512 + t;               // 0..2047
            const int r1 = s1 >> 5, sc1 = s1 & 31;
            const int gc1 = (sc1 & ~7) | ((sc1 & 7) ^ (r1 & 7));
            GLL16(w1 + (size_t)(hc * 64 + r1) * 256 + gc1 * 8, &W1s[s1 * 8]);
        }
#pragma unroll
        for (int j = 0; j < 4; ++j) {
            const int s2 = j * 512 + t;
            const int r2 = s2 >> 3, sc2 = s2 & 7;
            const int gc2 = sc2 ^ (r2 & 7);
            GLL16(w2 + (size_t)r2 * 1024 + hc * 64 + gc2 * 8, &W2s[s2 * 8]);
        }
        __syncthreads();   // As (first iter) + W chunks ready

        // ---- h-phase: h[128,64] chunk; wave tile rows wm*64, cols wn*16 ----
        f32x4 acch[4] = {};
#pragma unroll
        for (int ks = 0; ks < 8; ++ks) {
            const int c = ks * 4 + kc;                // global k-chunk 0..31
            const int rb = wn * 16 + lr;              // 0..63
            const bf16x8 bfr = *(const bf16x8*)
                &W1s[rb * 256 + ((c & ~7) | ((c & 7) ^ (rb & 7))) * 8];
#pragma unroll
            for (int i = 0; i < 4; ++i) {
                const int ra = wm * 64 + i * 16 + lr;
                const bf16x8 afr = *(const bf16x8*)
                    &As[ra * 256 + ((c & ~7) | ((c & 7) ^ (ra & 7))) * 8];
                acch[i] = __builtin_amdgcn_mfma_f32_16x16x32_bf16(
                    afr, bfr, acch[i], 0, 0, 0);
            }
        }
        // relu + bias -> Hs (bf16, swizzled)
        {
            const int hcol = wn * 16 + cl;            // 0..63
            const float bv1 = b1p[hc * 64 + hcol];
#pragma unroll
            for (int i = 0; i < 4; ++i)
#pragma unroll
                for (int r = 0; r < 4; ++r) {
                    const int hr = wm * 64 + i * 16 + rq + r;
                    const float v = fmaxf(acch[i][r] + bv1, 0.f);
                    Hs[hr * 64 + (((hcol >> 3) ^ (hr & 7)) * 8) + (hcol & 7)] = f2bf(v);
                }
        }
        __syncthreads();   // Hs ready

        // ---- out-phase: out[128,256] += h @ W2c^T (k = 64) ----
#pragma unroll
        for (int ks = 0; ks < 2; ++ks) {
            const int c = ks * 4 + kc;                // 0..7
            bf16x8 af2[4], bf2[4];
#pragma unroll
            for (int i = 0; i < 4; ++i) {
                const int ra = wm * 64 + i * 16 + lr;
                af2[i] = *(const bf16x8*)&Hs[ra * 64 + (c ^ (ra & 7)) * 8];
            }
#pragma unroll
            for (int j = 0; j < 4; ++j) {
                const int rb = wn * 64 + j * 16 + lr;
                bf2[j] = *(const bf16x8*)&W2s[rb * 64 + (c ^ (rb & 7)) * 8];
            }
#pragma unroll
            for (int i = 0; i < 4; ++i)
#pragma unroll
                for (int j = 0; j < 4; ++j)
                    acc[i][j] = __builtin_amdgcn_mfma_f32_16x16x32_bf16(
                        af2[i], bf2[j], acc[i][j], 0, 0, 0);
        }
        __syncthreads();   // protect W1s/W2s/Hs before next stage
    }

    // ---- epilogue: + b2 + residual(xo), write fp32 in place ----
#pragma unroll
    for (int i = 0; i < 4; ++i)
#pragma unroll
        for (int j = 0; j < 4; ++j) {
            const int col = wn * 64 + j * 16 + cl;
            const float bv = b2p[col];
#pragma unroll
            for (int r = 0; r < 4; ++r) {
                const int row = m0 + wm * 64 + i * 16 + rq + r;
                const size_t o = (size_t)row * 256 + col;
                xo[o] = acc[i][j][r] + bv + xo[o];
            }
        }
}

// ---------- launch ----------
// fp32 I/O, bf16 internal, fp32 residual trunk on d_out.
// ws layout (ushort elems): weights [0,786432); xn [1M,17M); att [17M,33M);
// qkvb [33M,81M). Phase B needs only the weights.
extern "C" void kernel_launch(void* const* d_in, const int* in_sizes, int n_in,
                              void* d_out, int out_size, void* d_ws, size_t ws_size,
                              hipStream_t stream)
{
    const float* x      = (const float*)d_in[0];
    const float* ln1_g  = (const float*)d_in[1];
    const float* ln1_b  = (const float*)d_in[2];
    const float* qkv_w  = (const float*)d_in[3];
    const float* qkv_b  = (const float*)d_in[4];
    const float* proj_w = (const float*)d_in[5];
    const float* proj_b = (const float*)d_in[6];
    const float* ln2_g  = (const float*)d_in[7];
    const float* ln2_b  = (const float*)d_in[8];
    const float* ffn_w1 = (const float*)d_in[9];
    const float* ffn_b1 = (const float*)d_in[10];
    const float* ffn_w2 = (const float*)d_in[11];
    const float* ffn_b2 = (const float*)d_in[12];
    float* xo = (float*)d_out;            // fp32 trunk + final out

    const int M = 65536;
    const size_t MEG = 1024 * 1024;
    unsigned short* ws = (unsigned short*)d_ws;
    unsigned short* qkv_wb  = ws;                   // 196608
    unsigned short* proj_wb = ws + 196608;          // 65536
    unsigned short* ffn_w1b = ws + 262144;          // 262144
    unsigned short* ffn_w2b = ws + 524288;          // 262144
    unsigned short* xn   = ws + 1 * MEG;            // [M,256]
    unsigned short* att  = ws + 17 * MEG;           // [M,256]
    unsigned short* qkvb = ws + 33 * MEG;           // [M,768]

    cvt4_kernel<<<768, 256, 0, stream>>>(qkv_w, proj_w, ffn_w1, ffn_w2, ws);

    ln_kernel<<<M / 4, 256, 0, stream>>>(x, ln1_g, ln1_b, xn);
    gemm_bt<0, 0, 0><<<dim3(M / 128, 6), 256, 0, stream>>>(
        xn, qkv_wb, qkv_b, nullptr, qkvb, M, 768, 256);
    attn_headmix<<<M / 4, 256, 0, stream>>>(qkvb, att, M);
    gemm_bt<0, 1, 1><<<dim3(M / 128, 2), 256, 0, stream>>>(
        att, proj_wb, proj_b, x, xo, M, 256, 256);
    ffn_fused<<<M / 128, 512, 0, stream>>>(
        xo, ln2_g, ln2_b, ffn_w1b, ffn_b1, ffn_w2b, ffn_b2);
}

// Round 7
// 420.618 us; speedup vs baseline: 1.4169x; 1.1029x over previous
//
#include <hip/hip_runtime.h>
#include <hip/hip_bf16.h>
#include <stdint.h>

// ---------- types / helpers ----------
typedef float f32x4 __attribute__((ext_vector_type(4)));
typedef __bf16 bf16x8 __attribute__((ext_vector_type(8)));
typedef unsigned short ushort8 __attribute__((ext_vector_type(8)));

__device__ __forceinline__ float bf2f(unsigned short u) {
    unsigned int x = ((unsigned int)u) << 16;
    return __builtin_bit_cast(float, x);
}
__device__ __forceinline__ unsigned short f2bf(float f) {
    unsigned int x = __builtin_bit_cast(unsigned int, f);
    unsigned int lsb = (x >> 16) & 1u;
    x += 0x7fffu + lsb;            // round-to-nearest-even
    return (unsigned short)(x >> 16);
}

#define GLL16(gptr, lptr)                                                      \
    __builtin_amdgcn_global_load_lds(                                          \
        (const __attribute__((address_space(1))) void*)(gptr),                 \
        (__attribute__((address_space(3))) void*)(lptr), 16, 0, 0)

// ---------- fp32 -> bf16 convert, all 4 weight matrices in one launch ----------
__global__ __launch_bounds__(256) void cvt4_kernel(
    const float* __restrict__ w0, const float* __restrict__ w1,
    const float* __restrict__ w2, const float* __restrict__ w3,
    unsigned short* __restrict__ dst)
{
    const int i = blockIdx.x * 256 + threadIdx.x;   // 0..196607
    const float* s; int off;
    if      (i <  49152) { s = w0; off = 0; }
    else if (i <  65536) { s = w1; off = 49152; }
    else if (i < 131072) { s = w2; off = 65536; }
    else                 { s = w3; off = 131072; }
    f32x4 v = ((const f32x4*)s)[i - off];
    ushort4 o;
    o.x = f2bf(v.x); o.y = f2bf(v.y); o.z = f2bf(v.z); o.w = f2bf(v.w);
    ((ushort4*)dst)[i] = o;
}

// ---------- LayerNorm (LN1): fp32 in -> bf16 out, one wave per token ----------
__global__ __launch_bounds__(256) void ln_kernel(
    const float* __restrict__ x, const float* __restrict__ g,
    const float* __restrict__ b, unsigned short* __restrict__ y)
{
    const int lane = threadIdx.x & 63, wave = threadIdx.x >> 6;
    const size_t tok = (size_t)blockIdx.x * 4 + wave;
    f32x4 v = *(const f32x4*)(x + tok * 256 + lane * 4);
    float s = v.x + v.y + v.z + v.w;
    float q = v.x * v.x + v.y * v.y + v.z * v.z + v.w * v.w;
#pragma unroll
    for (int o = 32; o; o >>= 1) {
        s += __shfl_xor(s, o, 64);
        q += __shfl_xor(q, o, 64);
    }
    float mean = s * (1.f / 256.f);
    float var  = q * (1.f / 256.f) - mean * mean;
    float rstd = rsqrtf(var + 1e-5f);
    f32x4 gr = *(const f32x4*)(g + lane * 4);
    f32x4 br = *(const f32x4*)(b + lane * 4);
    ushort4 o4;
    o4.x = f2bf((v.x - mean) * rstd * gr.x + br.x);
    o4.y = f2bf((v.y - mean) * rstd * gr.y + br.y);
    o4.z = f2bf((v.z - mean) * rstd * gr.z + br.z);
    o4.w = f2bf((v.w - mean) * rstd * gr.w + br.w);
    *(ushort4*)(y + tok * 256 + lane * 4) = o4;
}

// ---------- GEMM (phase A: qkv / proj) ----------
// 1-D grid with XCD-aware decode: the nby n-strip siblings that share an
// A-tile get consecutive slots on the SAME XCD -> A stage is L2-hot.
template <int RELU, int HASRES, int OUTF32>
__global__ __launch_bounds__(256) void gemm_bt(
    const unsigned short* __restrict__ A,    // [M,K] bf16
    const unsigned short* __restrict__ W,    // [N,K] bf16
    const float* __restrict__ bias,          // [N]   fp32
    const float* res,                        // [M,N] fp32 or null
    void* Cv,                                // [M,N] bf16 or fp32
    int M, int N, int K, int nby)
{
    __shared__ __align__(16) unsigned short As[128 * 64];
    __shared__ __align__(16) unsigned short Bs[128 * 64];

    const int t    = threadIdx.x;
    const int id   = blockIdx.x;
    const int xcd  = id & 7;
    const int sl   = id >> 3;
    const int by   = sl % nby;
    const int bx   = (sl / nby) * 8 + xcd;
    const int m0   = bx * 128;
    const int n0   = by * 128;
    const int lane = t & 63;
    const int wave = t >> 6;
    const int wm = wave & 1, wn = wave >> 1;
    const int lr = lane & 15, kc = lane >> 4;

    f32x4 acc[4][4] = {};

    const int rA   = t >> 3;                       // 0..31
    const int gcol = ((t & 7) ^ (rA & 7)) * 8;
    const unsigned short* gA = A + (size_t)(m0 + rA) * K + gcol;
    const unsigned short* gB = W + (size_t)(n0 + rA) * K + gcol;

    for (int k0 = 0; k0 < K; k0 += 64) {
#pragma unroll
        for (int w = 0; w < 4; ++w) {
            GLL16(gA + (size_t)(w * 32) * K + k0, &As[(w * 256 + t) * 8]);
            GLL16(gB + (size_t)(w * 32) * K + k0, &Bs[(w * 256 + t) * 8]);
        }
        __syncthreads();

#pragma unroll
        for (int hh = 0; hh < 2; ++hh) {
            bf16x8 af[4], bf[4];
#pragma unroll
            for (int i = 0; i < 4; ++i) {
                const int ra = wm * 64 + i * 16 + lr;
                const int rb = wn * 64 + i * 16 + lr;
                af[i] = *(const bf16x8*)&As[ra * 64 + ((hh * 4 + kc) ^ (ra & 7)) * 8];
                bf[i] = *(const bf16x8*)&Bs[rb * 64 + ((hh * 4 + kc) ^ (rb & 7)) * 8];
            }
#pragma unroll
            for (int i = 0; i < 4; ++i)
#pragma unroll
                for (int j = 0; j < 4; ++j)
                    acc[i][j] = __builtin_amdgcn_mfma_f32_16x16x32_bf16(
                        af[i], bf[j], acc[i][j], 0, 0, 0);
        }
        __syncthreads();
    }

    float* Cf = (float*)Cv;
    unsigned short* Cb = (unsigned short*)Cv;
    const int row0 = m0 + wm * 64;
    const int col0 = n0 + wn * 64;
    const int cl = lane & 15;
    const int rq = (lane >> 4) * 4;
#pragma unroll
    for (int i = 0; i < 4; ++i) {
#pragma unroll
        for (int j = 0; j < 4; ++j) {
            const int col = col0 + j * 16 + cl;
            const float bv = bias[col];
#pragma unroll
            for (int r = 0; r < 4; ++r) {
                const int row = row0 + i * 16 + rq + r;
                float v = acc[i][j][r] + bv;
                if (RELU) v = fmaxf(v, 0.f);
                const size_t o = (size_t)row * N + col;
                if (HASRES) v += res[o];
                if (OUTF32) Cf[o] = v;
                else        Cb[o] = f2bf(v);
            }
        }
    }
}

// ---------- Per-token head-mix attention (bf16 in/out), unchanged ----------
__global__ __launch_bounds__(256) void attn_headmix(
    const unsigned short* __restrict__ qkv,  // [T,768] bf16
    unsigned short* __restrict__ out,        // [T,256] bf16
    int T)
{
    const int lane = threadIdx.x & 63, wave = threadIdx.x >> 6;
    const int tok = blockIdx.x * 4 + wave;
    if (tok >= T) return;
    const unsigned short* base = qkv + (size_t)tok * 768;
    const int h = lane >> 3, g = lane & 7;

    float s = 0.f;
#pragma unroll
    for (int d8 = 0; d8 < 4; ++d8) {
        ushort4 qa = *(const ushort4*)(base + h * 32 + d8 * 8);
        ushort4 qb = *(const ushort4*)(base + h * 32 + d8 * 8 + 4);
        ushort4 ka = *(const ushort4*)(base + 256 + g * 32 + d8 * 8);
        ushort4 kb = *(const ushort4*)(base + 256 + g * 32 + d8 * 8 + 4);
        s += bf2f(qa.x) * bf2f(ka.x) + bf2f(qa.y) * bf2f(ka.y)
           + bf2f(qa.z) * bf2f(ka.z) + bf2f(qa.w) * bf2f(ka.w)
           + bf2f(qb.x) * bf2f(kb.x) + bf2f(qb.y) * bf2f(kb.y)
           + bf2f(qb.z) * bf2f(kb.z) + bf2f(qb.w) * bf2f(kb.w);
    }
    s *= 0.17677669529663687f;

    float mx = s;
#pragma unroll
    for (int o = 1; o < 8; o <<= 1) mx = fmaxf(mx, __shfl_xor(mx, o, 64));
    float e = __expf(s - mx);
    float sum = e;
#pragma unroll
    for (int o = 1; o < 8; o <<= 1) sum += __shfl_xor(sum, o, 64);
    const float a = e / sum;

    float o0 = 0.f, o1 = 0.f, o2 = 0.f, o3 = 0.f;
#pragma unroll
    for (int gg = 0; gg < 8; ++gg) {
        const float ag = __shfl(a, (lane & 56) | gg, 64);
        ushort4 vv = *(const ushort4*)(base + 512 + gg * 32 + g * 4);
        o0 += ag * bf2f(vv.x);
        o1 += ag * bf2f(vv.y);
        o2 += ag * bf2f(vv.z);
        o3 += ag * bf2f(vv.w);
    }
    ushort4 ov;
    ov.x = f2bf(o0); ov.y = f2bf(o1); ov.z = f2bf(o2); ov.w = f2bf(o3);
    *(ushort4*)(out + (size_t)tok * 256 + lane * 4) = ov;
}

// ---------- Fused LN2 + FFN1(relu) + FFN2 + residual, in-place on xo ----------
// Block = 128 rows, 512 threads (8 waves, 2x4). LDS 146 KB, 1 block/CU.
// Phase 0: LN2 -> As (in U). Then each lane register-caches its 32 A
// fragments (128 VGPRs) and U is reused as the SECOND W double-buffer.
// 16 hidden chunks of 64, double-buffered W staging. CRITICAL: chunk hc+2
// has the SAME parity as hc, so the prefetch at the end of hc goes into the
// JUST-CONSUMED buffers (W1c/W2c) — NOT the other pair (R6 bug: overwrote
// the unconsumed hc+1 weights).
__global__ __launch_bounds__(512, 2) void ffn_fused(
    float* xo,                               // [M,256] fp32, read + written
    const float* __restrict__ ln2_g, const float* __restrict__ ln2_b,
    const unsigned short* __restrict__ w1,   // [1024,256] bf16
    const float* __restrict__ b1p,           // [1024]
    const unsigned short* __restrict__ w2,   // [256,1024] bf16
    const float* __restrict__ b2p)           // [256]
{
    __shared__ __align__(16) unsigned short U[32768];      // 64 KB: As, then W1b|W2b
    __shared__ __align__(16) unsigned short W1a[16384];    // 32 KB
    __shared__ __align__(16) unsigned short W2a[16384];    // 32 KB
    __shared__ __align__(16) unsigned short Hs[128 * 72];  // 18 KB

    unsigned short* const W1b = U;
    unsigned short* const W2b = U + 16384;

    const int t = threadIdx.x;               // 0..511
    const int lane = t & 63, wave = t >> 6;
    const int m0 = blockIdx.x * 128;
    const int lr = lane & 15, kc = lane >> 4;
    const int cl = lane & 15, rq = (lane >> 4) * 4;
    const int wm = wave & 1, wn = wave >> 1; // wn in 0..3

    // staging index precompute (j-invariant parts)
    const int r1b = t >> 5;                  // W1 row base 0..15
    const int sc1 = t & 31;
    const int gc1 = (sc1 & ~7) | ((sc1 & 7) ^ (r1b & 7));
    const int r2b = t >> 3;                  // W2 row base 0..63
    const int gc2 = (t & 7) ^ (r2b & 7);

    #define STAGE_W(hp, W1t, W2t)                                              \
        {                                                                      \
            _Pragma("unroll")                                                  \
            for (int j = 0; j < 4; ++j)                                        \
                GLL16(w1 + (size_t)((hp) * 64 + j * 16 + r1b) * 256 + gc1 * 8, \
                      &(W1t)[(j * 512 + t) * 8]);                              \
            _Pragma("unroll")                                                  \
            for (int j = 0; j < 4; ++j)                                        \
                GLL16(w2 + (size_t)(j * 64 + r2b) * 1024 + (hp) * 64 + gc2 * 8,\
                      &(W2t)[(j * 512 + t) * 8]);                              \
        }

    STAGE_W(0, W1a, W2a);                    // in flight during phase 0

    // ---- phase 0: LN2 of the 128-row tile -> bf16 As in U (swizzled) ----
    {
        const int row0 = t >> 2;             // 0..127
        const int seg  = t & 3;              // 64-float segment
        const float* xrp = xo + (size_t)(m0 + row0) * 256 + seg * 64;
        f32x4 xv[16];
#pragma unroll
        for (int i = 0; i < 16; ++i) xv[i] = ((const f32x4*)xrp)[i];
        float s = 0.f, q = 0.f;
#pragma unroll
        for (int i = 0; i < 16; ++i) {
            s += xv[i].x + xv[i].y + xv[i].z + xv[i].w;
            q += xv[i].x * xv[i].x + xv[i].y * xv[i].y
               + xv[i].z * xv[i].z + xv[i].w * xv[i].w;
        }
        s += __shfl_xor(s, 1, 64); q += __shfl_xor(q, 1, 64);
        s += __shfl_xor(s, 2, 64); q += __shfl_xor(q, 2, 64);
        const float mean = s * (1.f / 256.f);
        const float rstd = rsqrtf(q * (1.f / 256.f) - mean * mean + 1e-5f);
#pragma unroll
        for (int c8 = 0; c8 < 8; ++c8) {
            const f32x4 g0 = ((const f32x4*)(ln2_g + seg * 64 + c8 * 8))[0];
            const f32x4 g1 = ((const f32x4*)(ln2_g + seg * 64 + c8 * 8))[1];
            const f32x4 bb0 = ((const f32x4*)(ln2_b + seg * 64 + c8 * 8))[0];
            const f32x4 bb1 = ((const f32x4*)(ln2_b + seg * 64 + c8 * 8))[1];
            const f32x4 a0 = xv[c8 * 2], a1 = xv[c8 * 2 + 1];
            ushort8 o;
            o[0] = f2bf((a0.x - mean) * rstd * g0.x + bb0.x);
            o[1] = f2bf((a0.y - mean) * rstd * g0.y + bb0.y);
            o[2] = f2bf((a0.z - mean) * rstd * g0.z + bb0.z);
            o[3] = f2bf((a0.w - mean) * rstd * g0.w + bb0.w);
            o[4] = f2bf((a1.x - mean) * rstd * g1.x + bb1.x);
            o[5] = f2bf((a1.y - mean) * rstd * g1.y + bb1.y);
            o[6] = f2bf((a1.z - mean) * rstd * g1.z + bb1.z);
            o[7] = f2bf((a1.w - mean) * rstd * g1.w + bb1.w);
            const int gc = seg * 8 + c8;     // global chunk 0..31
            const int sc = (gc & ~7) | ((gc & 7) ^ (row0 & 7));
            *(ushort8*)&U[row0 * 256 + sc * 8] = o;
        }
    }
    __syncthreads();   // As ready; W(0) landed (vmcnt drained)

    // ---- register-cache this wave's A fragments (rows wm*64..+63, all K) ----
    bf16x8 afr[4][8];
#pragma unroll
    for (int i = 0; i < 4; ++i) {
        const int ra = wm * 64 + i * 16 + lr;
#pragma unroll
        for (int ks = 0; ks < 8; ++ks) {
            const int c = ks * 4 + kc;
            afr[i][ks] = *(const bf16x8*)
                &U[ra * 256 + ((c & ~7) | ((c & 7) ^ (ra & 7))) * 8];
        }
    }
    __syncthreads();   // all waves done reading U -> it becomes W buffer B
    STAGE_W(1, W1b, W2b);

    f32x4 acc[4][4] = {};                    // out tile: rows wm*64, cols wn*64

    for (int hc = 0; hc < 16; ++hc) {
        unsigned short* const W1c = (hc & 1) ? W1b : W1a;
        unsigned short* const W2c = (hc & 1) ? W2b : W2a;

        // ---- h-phase: acch[i] = A(rows) @ W1c^T(cols wn*16+lr) ----
        f32x4 acch[4] = {};
#pragma unroll
        for (int ks = 0; ks < 8; ++ks) {
            const int c = ks * 4 + kc;
            const int rb = wn * 16 + lr;
            const bf16x8 bfr = *(const bf16x8*)
                &W1c[rb * 256 + ((c & ~7) | ((c & 7) ^ (rb & 7))) * 8];
#pragma unroll
            for (int i = 0; i < 4; ++i)
                acch[i] = __builtin_amdgcn_mfma_f32_16x16x32_bf16(
                    afr[i][ks], bfr, acch[i], 0, 0, 0);
        }
        // relu + bias -> Hs (stride 72, no swizzle)
        {
            const int hcol = wn * 16 + cl;
            const float bv1 = b1p[hc * 64 + hcol];
#pragma unroll
            for (int i = 0; i < 4; ++i)
#pragma unroll
                for (int r = 0; r < 4; ++r) {
                    const int hr = wm * 64 + i * 16 + rq + r;
                    Hs[hr * 72 + hcol] = f2bf(fmaxf(acch[i][r] + bv1, 0.f));
                }
        }
        __syncthreads();   // B1: Hs ready; drain -> W(hc+1) landed

        // ---- out-phase: acc += h @ W2c^T (k = 64) ----
#pragma unroll
        for (int ks = 0; ks < 2; ++ks) {
            const int c = ks * 4 + kc;                // 0..7
            bf16x8 bw[4];
#pragma unroll
            for (int j = 0; j < 4; ++j) {
                const int rb = wn * 64 + j * 16 + lr;
                bw[j] = *(const bf16x8*)&W2c[rb * 64 + ((c ^ (rb & 7)) * 8)];
            }
#pragma unroll
            for (int i = 0; i < 4; ++i) {
                const int ra = wm * 64 + i * 16 + lr;
                const bf16x8 ah = *(const bf16x8*)&Hs[ra * 72 + c * 8];
#pragma unroll
                for (int j = 0; j < 4; ++j)
                    acc[i][j] = __builtin_amdgcn_mfma_f32_16x16x32_bf16(
                        ah, bw[j], acc[i][j], 0, 0, 0);
            }
        }
        __syncthreads();   // B2: current buffers + Hs free
        // prefetch hc+2 (same parity) into the JUST-CONSUMED buffers
        if (hc < 14) STAGE_W(hc + 2, W1c, W2c);
    }

    // ---- epilogue: + b2 + residual(xo), write fp32 in place ----
#pragma unroll
    for (int i = 0; i < 4; ++i)
#pragma unroll
        for (int j = 0; j < 4; ++j) {
            const int col = wn * 64 + j * 16 + cl;
            const float bv = b2p[col];
#pragma unroll
            for (int r = 0; r < 4; ++r) {
                const int row = m0 + wm * 64 + i * 16 + rq + r;
                const size_t o = (size_t)row * 256 + col;
                xo[o] = acc[i][j][r] + bv + xo[o];
            }
        }
    #undef STAGE_W
}

// ---------- launch ----------
// fp32 I/O, bf16 internal, fp32 residual trunk on d_out.
// ws layout (ushort elems): weights [0,786432); xn [1M,17M); att [17M,33M);
// qkvb [33M,81M).
extern "C" void kernel_launch(void* const* d_in, const int* in_sizes, int n_in,
                              void* d_out, int out_size, void* d_ws, size_t ws_size,
                              hipStream_t stream)
{
    const float* x      = (const float*)d_in[0];
    const float* ln1_g  = (const float*)d_in[1];
    const float* ln1_b  = (const float*)d_in[2];
    const float* qkv_w  = (const float*)d_in[3];
    const float* qkv_b  = (const float*)d_in[4];
    const float* proj_w = (const float*)d_in[5];
    const float* proj_b = (const float*)d_in[6];
    const float* ln2_g  = (const float*)d_in[7];
    const float* ln2_b  = (const float*)d_in[8];
    const float* ffn_w1 = (const float*)d_in[9];
    const float* ffn_b1 = (const float*)d_in[10];
    const float* ffn_w2 = (const float*)d_in[11];
    const float* ffn_b2 = (const float*)d_in[12];
    float* xo = (float*)d_out;            // fp32 trunk + final out

    const int M = 65536;
    const size_t MEG = 1024 * 1024;
    unsigned short* ws = (unsigned short*)d_ws;
    unsigned short* qkv_wb  = ws;                   // 196608
    unsigned short* proj_wb = ws + 196608;          // 65536
    unsigned short* ffn_w1b = ws + 262144;          // 262144
    unsigned short* ffn_w2b = ws + 524288;          // 262144
    unsigned short* xn   = ws + 1 * MEG;            // [M,256]
    unsigned short* att  = ws + 17 * MEG;           // [M,256]
    unsigned short* qkvb = ws + 33 * MEG;           // [M,768]

    cvt4_kernel<<<768, 256, 0, stream>>>(qkv_w, proj_w, ffn_w1, ffn_w2, ws);

    ln_kernel<<<M / 4, 256, 0, stream>>>(x, ln1_g, ln1_b, xn);
    gemm_bt<0, 0, 0><<<3072, 256, 0, stream>>>(
        xn, qkv_wb, qkv_b, nullptr, qkvb, M, 768, 256, 6);
    attn_headmix<<<M / 4, 256, 0, stream>>>(qkvb, att, M);
    gemm_bt<0, 1, 1><<<1024, 256, 0, stream>>>(
        att, proj_wb, proj_b, x, xo, M, 256, 256, 2);
    ffn_fused<<<M / 128, 512, 0, stream>>>(
        xo, ln2_g, ln2_b, ffn_w1b, ffn_b1, ffn_w2b, ffn_b2);
}